// Round 14
// baseline (1313.652 us; speedup 1.0000x reference)
//
#include <hip/hip_runtime.h>
#include <hip/hip_bf16.h>
#include <math.h>

#define NPOS 10000
#define NANCH 30000
#define PRE 2000
#define POST 1000
#define RESQ 4096
#define CLAMPD 4.135166556742356
#define FPH 102
#define FPW 132

typedef __attribute__((ext_vector_type(8))) short bf16x8v;
typedef __attribute__((ext_vector_type(4))) float f32x4v;

__device__ __forceinline__ unsigned long long mapu64(double f) {
  unsigned long long b = (unsigned long long)__double_as_longlong(f);
  return (b & 0x8000000000000000ULL) ? ~b : (b | 0x8000000000000000ULL);
}
__device__ __forceinline__ unsigned mapu32(float f) {
  unsigned b = __float_as_uint(f);
  return (b & 0x80000000u) ? ~b : (b | 0x80000000u);
}

__device__ __forceinline__ void async_load16(const void* g, void* l) {
  __builtin_amdgcn_global_load_lds((const __attribute__((address_space(1))) void*)g,
                                   (__attribute__((address_space(3))) void*)l, 16, 0, 0);
}

// ---------------- conv weights: w[co][ci][tap] (f32) -> wT64r[tap][ci][co] (f64) ----------------
__global__ void repack_w_k(const float* __restrict__ w, double* __restrict__ wT64r) {
  int tid = blockIdx.x * 256 + threadIdx.x;
  if (tid >= 589824) return;
  int co = tid / 2304;
  int rem = tid % 2304;        // ci*9 + tap
  int ci = rem / 9, tap = rem % 9;
  wT64r[((size_t)tap * 256 + ci) * 256 + co] = (double)w[tid];
}

// ---------------- conv weights: -> wBt[tap][co][ci] bf16 ----------------
__global__ void wbt_k(const float* __restrict__ w, __hip_bfloat16* __restrict__ wBt) {
  int i = blockIdx.x * 256 + threadIdx.x;
  if (i >= 589824) return;
  int tap = i >> 16;
  int co = (i >> 8) & 255;
  int ci = i & 255;
  wBt[i] = __float2bfloat16(w[(co * 256 + ci) * 9 + tap]);
}

// ---------------- features NCHW -> NHWC (featT[b][pos][c], f32) ----------------
__global__ void transpose_feat_k(const float* __restrict__ feat, float* __restrict__ featT) {
  __shared__ float tile[32][33];
  int b = blockIdx.z;
  int c0 = blockIdx.y * 32;
  int p0 = blockIdx.x * 32;
  int tx = threadIdx.x & 31, ty = threadIdx.x >> 5;
  for (int r = 0; r < 4; ++r) {
    int c = c0 + ty + r * 8, p = p0 + tx;
    tile[ty + r * 8][tx] = (p < NPOS) ? feat[((size_t)b * 256 + c) * NPOS + p] : 0.f;
  }
  __syncthreads();
  for (int r = 0; r < 4; ++r) {
    int p = p0 + ty + r * 8, c = c0 + tx;
    if (p < NPOS) featT[((size_t)b * NPOS + p) * 256 + c] = tile[tx][ty + r * 8];
  }
}

// ---------------- zero fpadB ----------------
__global__ void fpad_zero_k(__hip_bfloat16* __restrict__ f) {
  size_t i = (size_t)blockIdx.x * 256 + threadIdx.x;
  uint4 z = {0, 0, 0, 0};
  ((uint4*)f)[i] = z;
}

// ---------------- fill fpadB[b][y+1][x+1][c] = bf16(feat[b][c][y*100+x]) ----------------
__global__ void fpad_fill_k(const float* __restrict__ feat, __hip_bfloat16* __restrict__ fpadB) {
  __shared__ float tile[32][33];
  int b = blockIdx.z;
  int c0 = blockIdx.y * 32;
  int p0 = blockIdx.x * 32;
  int tx = threadIdx.x & 31, ty = threadIdx.x >> 5;
  for (int r = 0; r < 4; ++r) {
    int c = c0 + ty + r * 8, p = p0 + tx;
    tile[ty + r * 8][tx] = (p < NPOS) ? feat[((size_t)b * 256 + c) * NPOS + p] : 0.f;
  }
  __syncthreads();
  for (int r = 0; r < 4; ++r) {
    int p = p0 + ty + r * 8, c = c0 + tx;
    if (p < NPOS) {
      int y = p / 100, x = p % 100;
      fpadB[(((size_t)b * FPH + y + 1) * FPW + (x + 1)) * 256 + c] =
          __float2bfloat16(tile[tx][ty + r * 8]);
    }
  }
}

// ---------------- 3x3 conv via bf16 MFMA ----------------
__global__ __launch_bounds__(256) void conv_mfma_k(const __hip_bfloat16* __restrict__ fpadB,
                                                   const __hip_bfloat16* __restrict__ wBt,
                                                   const float* __restrict__ bias,
                                                   float* __restrict__ t32) {
  __shared__ __hip_bfloat16 As[128 * 64];
  __shared__ __hip_bfloat16 Bs[128 * 64];
  const int t = threadIdx.x;
  const int wv = t >> 6;
  const int lane = t & 63;
  const int lr = lane & 15, lg = lane >> 4;
  const int wr = wv >> 1, wc = wv & 1;
  const int co0 = blockIdx.x * 128;
  const int mt = blockIdx.y;
  const int img = mt / 100;
  const int rem = mt % 100;
  const int y0 = (rem / 4) * 4, x0 = (rem % 4) * 32;

  f32x4v acc[4][4];
#pragma unroll
  for (int i = 0; i < 4; ++i)
#pragma unroll
    for (int j = 0; j < 4; ++j)
#pragma unroll
      for (int r = 0; r < 4; ++r) acc[i][j][r] = 0.f;

  int srow[4], sseg[4];
#pragma unroll
  for (int i = 0; i < 4; ++i) {
    int c = i * 256 + t;
    srow[i] = c >> 3;
    sseg[i] = (c & 7) ^ (srow[i] & 7);
  }
  int arow[4], brow[4], sk[2];
#pragma unroll
  for (int ms = 0; ms < 4; ++ms) arow[ms] = (wr * 64 + ms * 16 + lr) * 128;
#pragma unroll
  for (int ns = 0; ns < 4; ++ns) brow[ns] = (wc * 64 + ns * 16 + lr) * 128;
#pragma unroll
  for (int kk = 0; kk < 2; ++kk) sk[kk] = (((kk * 4 + lg) ^ (lr & 7)) * 16);

  for (int chunk = 0; chunk < 36; ++chunk) {
    int tap = chunk >> 2;
    int ci0 = (chunk & 3) * 64;
    int dy = tap / 3, dx = tap % 3;
    __syncthreads();
#pragma unroll
    for (int i = 0; i < 4; ++i) {
      int r = srow[i];
      int py = y0 + (r >> 5) + dy, px = x0 + (r & 31) + dx;
      const __hip_bfloat16* ga =
          fpadB + ((((size_t)img * FPH + py) * FPW + px) << 8) + ci0 + sseg[i] * 8;
      async_load16(ga, (char*)As + ((i * 256 + wv * 64) * 16));
    }
#pragma unroll
    for (int i = 0; i < 4; ++i) {
      int r = srow[i];
      const __hip_bfloat16* gb =
          wBt + ((size_t)(tap * 256 + co0 + r) << 8) + ci0 + sseg[i] * 8;
      async_load16(gb, (char*)Bs + ((i * 256 + wv * 64) * 16));
    }
    __syncthreads();

    bf16x8v af[2][4], bf[2][4];
#pragma unroll
    for (int kk = 0; kk < 2; ++kk) {
#pragma unroll
      for (int ms = 0; ms < 4; ++ms)
        af[kk][ms] = *(const bf16x8v*)((const char*)As + arow[ms] + sk[kk]);
#pragma unroll
      for (int ns = 0; ns < 4; ++ns)
        bf[kk][ns] = *(const bf16x8v*)((const char*)Bs + brow[ns] + sk[kk]);
    }
#pragma unroll
    for (int ms = 0; ms < 4; ++ms)
#pragma unroll
      for (int ns = 0; ns < 4; ++ns) {
        acc[ms][ns] = __builtin_amdgcn_mfma_f32_16x16x32_bf16(af[0][ms], bf[0][ns], acc[ms][ns], 0, 0, 0);
        acc[ms][ns] = __builtin_amdgcn_mfma_f32_16x16x32_bf16(af[1][ms], bf[1][ns], acc[ms][ns], 0, 0, 0);
      }
  }

#pragma unroll
  for (int ms = 0; ms < 4; ++ms) {
    int mbase = wr * 64 + ms * 16 + lg * 4;
#pragma unroll
    for (int ns = 0; ns < 4; ++ns) {
      int gn = co0 + wc * 64 + ns * 16 + lr;
      float bv = bias[gn];
#pragma unroll
      for (int r = 0; r < 4; ++r) {
        int m = mbase + r;
        int y = y0 + (m >> 5), x = x0 + (m & 31);
        if (x < 100)
          t32[((size_t)(img * NPOS + y * 100 + x)) * 256 + gn] = fmaxf(acc[ms][ns][r] + bv, 0.f);
      }
    }
  }
}

// ---------------- approximate obj head (f32) from t32[pos][c] ----------------
__global__ void rpn_obj_k(const float* __restrict__ t32, const float* __restrict__ wcls,
                          const float* __restrict__ bcls, float* __restrict__ obj) {
  __shared__ float wl[3][256];
  int tid = threadIdx.x;
  for (int i = tid; i < 768; i += 256) wl[i / 256][i % 256] = wcls[i];
  __syncthreads();
  int gp = blockIdx.x * 256 + tid;
  if (gp >= 2 * NPOS) return;
  const float* tr = t32 + (size_t)gp * 256;
  float a0 = 0.f, a1 = 0.f, a2 = 0.f;
  for (int c = 0; c < 256; c += 4) {
    float4 v = *(const float4*)&tr[c];
    a0 += v.x * wl[0][c] + v.y * wl[0][c + 1] + v.z * wl[0][c + 2] + v.w * wl[0][c + 3];
    a1 += v.x * wl[1][c] + v.y * wl[1][c + 1] + v.z * wl[1][c + 2] + v.w * wl[1][c + 3];
    a2 += v.x * wl[2][c] + v.y * wl[2][c + 1] + v.z * wl[2][c + 2] + v.w * wl[2][c + 3];
  }
  int b = gp / NPOS, lp = gp % NPOS;
  obj[(size_t)b * NANCH + lp * 3 + 0] = a0 + bcls[0];
  obj[(size_t)b * NANCH + lp * 3 + 1] = a1 + bcls[1];
  obj[(size_t)b * NANCH + lp * 3 + 2] = a2 + bcls[2];
}

// ---------------- candidate select: f32 radix-select T(2000th) + band ----------------
__global__ __launch_bounds__(1024) void select_k(const float* __restrict__ obj,
                                                 unsigned* __restrict__ cand,
                                                 int* __restrict__ poslist,
                                                 int* __restrict__ counts, float delta) {
  int b = blockIdx.x;
  __shared__ unsigned hist[16][256];
  __shared__ unsigned posbm[320];
  __shared__ unsigned sh_prefix, sh_rem;
  __shared__ int sh_ac, sh_pc;
  int tid = threadIdx.x;
  int wid = tid >> 6;
  const float* ob = obj + (size_t)b * NANCH;

  if (tid == 0) { sh_prefix = 0; sh_rem = PRE; sh_ac = 0; sh_pc = 0; }
  for (int i = tid; i < 320; i += 1024) posbm[i] = 0;
  for (int shift = 24; shift >= 0; shift -= 8) {
    for (int i = tid; i < 16 * 256; i += 1024) ((unsigned*)hist)[i] = 0;
    __syncthreads();
    unsigned pref = sh_prefix;
    unsigned himask = (shift == 24) ? 0u : (0xFFFFFFFFu << (shift + 8));
    for (int i = tid; i < NANCH; i += 1024) {
      unsigned u = mapu32(ob[i]);
      if ((u & himask) == pref) atomicAdd(&hist[wid][(u >> shift) & 255], 1u);
    }
    __syncthreads();
    if (tid < 256) {
      unsigned s = hist[0][tid];
      for (int w = 1; w < 16; ++w) s += hist[w][tid];
      hist[0][tid] = s;
    }
    __syncthreads();
    if (tid == 0) {
      unsigned rem = sh_rem, pfx = sh_prefix;
      for (int bb = 255; bb >= 0; --bb) {
        unsigned c = hist[0][bb];
        if (rem > c) rem -= c;
        else { pfx |= ((unsigned)bb) << shift; break; }
      }
      sh_prefix = pfx; sh_rem = rem;
    }
    __syncthreads();
  }
  unsigned T = sh_prefix;
  float Tval = __uint_as_float((T & 0x80000000u) ? (T & 0x7FFFFFFFu) : ~T);
  float thr = Tval - delta;
  for (int i = tid; i < NANCH; i += 1024) {
    if (ob[i] >= thr) {
      int p = atomicAdd(&sh_ac, 1);
      if (p < RESQ) cand[(size_t)b * RESQ + p] = (unsigned)i;
      int pos = i / 3;
      atomicOr(&posbm[pos >> 5], 1u << (pos & 31));
    }
  }
  __syncthreads();
  for (int w = tid; w < 313; w += 1024) {
    unsigned word = posbm[w];
    while (word) {
      int bit = __builtin_ctz(word);
      word &= word - 1;
      int q = atomicAdd(&sh_pc, 1);
      if (q < RESQ) poslist[(size_t)b * RESQ + q] = w * 32 + bit;
    }
  }
  __syncthreads();
  if (tid == 0) {
    counts[b * 2 + 0] = min(sh_ac, RESQ);
    counts[b * 2 + 1] = min(sh_pc, RESQ);
  }
}

// ---------------- f64 rescore, 3-way tap-split GEMM partials ----------------
// z = img*3 + tapgroup; block = 64 pos x 64 co; thread = 4 pos x 4 co (co strided 16).
// A read DIRECTLY from featT into registers (same-ty lanes merge); B in LDS stride 65
// (conflict-free writes and reads). FMA order identical to previous version -> bit-identical.
__global__ __launch_bounds__(256) void rescore_t3_k(const float* __restrict__ featT,
                                                    const double* __restrict__ wT64r,
                                                    const int* __restrict__ poslist,
                                                    const int* __restrict__ counts,
                                                    double* __restrict__ t64p) {
  int z = blockIdx.z;
  int b = z / 3, tg = z % 3;
  int cnt = counts[b * 2 + 1];
  int mbase = blockIdx.y * 64;
  if (mbase >= cnt) return;
  int co0 = blockIdx.x * 64;
  __shared__ double Bs[32][65];
  __shared__ int sgy[64], sgx[64];
  int tid = threadIdx.x;
  int tx = tid & 15;           // co lane: co = co0 + tx + 16j
  int ty = tid >> 4;           // pos quad: p = ty*4 + {0..3}
  if (tid < 64) {
    int q = mbase + tid;
    int pos = poslist[(size_t)b * RESQ + (q < cnt ? q : (cnt - 1))];
    sgy[tid] = pos / 100;
    sgx[tid] = pos % 100;
  }
  __syncthreads();
  int myy[4], myx[4];
#pragma unroll
  for (int p = 0; p < 4; ++p) { myy[p] = sgy[ty * 4 + p]; myx[p] = sgx[ty * 4 + p]; }
  const float* fb = featT + (size_t)b * NPOS * 256;

  double acc[4][4] = {};       // [p][j]
  int bk = tid >> 3, bq = tid & 7;

  for (int tt = 0; tt < 3; ++tt) {
    int tap = tg * 3 + tt;
    int dy = tap / 3 - 1, dx = tap % 3 - 1;
    const float* rp[4];
    bool val[4];
#pragma unroll
    for (int p = 0; p < 4; ++p) {
      int gy = myy[p] + dy, gx = myx[p] + dx;
      val[p] = (gy >= 0 && gy < 100 && gx >= 0 && gx < 100);
      rp[p] = fb + (size_t)((val[p] ? gy : 0) * 100 + (val[p] ? gx : 0)) * 256;
    }
    for (int cc = 0; cc < 8; ++cc) {
      int ci0 = cc * 32;
      __syncthreads();
      {
        const double* gw = wT64r + ((size_t)(tap * 256 + ci0 + bk)) * 256 + co0 + bq * 8;
#pragma unroll
        for (int i = 0; i < 4; ++i)
          *(double2*)&Bs[bk][bq * 8 + i * 2] = *(const double2*)(gw + i * 2);
      }
      __syncthreads();
#pragma unroll
      for (int g = 0; g < 4; ++g) {
        float a8[4][8];
#pragma unroll
        for (int p = 0; p < 4; ++p) {
          float4 v0 = {0.f, 0.f, 0.f, 0.f}, v1 = {0.f, 0.f, 0.f, 0.f};
          if (val[p]) {
            v0 = *(const float4*)(rp[p] + ci0 + g * 8);
            v1 = *(const float4*)(rp[p] + ci0 + g * 8 + 4);
          }
          a8[p][0] = v0.x; a8[p][1] = v0.y; a8[p][2] = v0.z; a8[p][3] = v0.w;
          a8[p][4] = v1.x; a8[p][5] = v1.y; a8[p][6] = v1.z; a8[p][7] = v1.w;
        }
#pragma unroll
        for (int kk = 0; kk < 8; ++kk) {
          int kki = g * 8 + kk;
          double b0 = Bs[kki][tx];
          double b1 = Bs[kki][tx + 16];
          double b2 = Bs[kki][tx + 32];
          double b3 = Bs[kki][tx + 48];
#pragma unroll
          for (int p = 0; p < 4; ++p) {
            double a = (double)a8[p][kk];
            acc[p][0] += a * b0;
            acc[p][1] += a * b1;
            acc[p][2] += a * b2;
            acc[p][3] += a * b3;
          }
        }
      }
    }
  }
#pragma unroll
  for (int p = 0; p < 4; ++p) {
    int gp = mbase + ty * 4 + p;
    if (gp >= cnt) continue;
    double* outp = t64p + (((size_t)tg * 2 + b) * RESQ + gp) * 256 + co0;
#pragma unroll
    for (int j = 0; j < 4; ++j) outp[tx + 16 * j] = acc[p][j];
  }
}

// ---------------- f64 heads: t = relu(p0+p1+p2+bias); obj/deltas dots ----------------
__global__ __launch_bounds__(256) void rescore_heads_k(const double* __restrict__ t64p,
                                                       const float* __restrict__ bias,
                                                       const int* __restrict__ poslist,
                                                       const int* __restrict__ counts,
                                                       const float* __restrict__ wcls,
                                                       const float* __restrict__ bcls,
                                                       const float* __restrict__ wbbox,
                                                       const float* __restrict__ bbbox,
                                                       double* __restrict__ obj64,
                                                       double* __restrict__ deltas64) {
  int b = blockIdx.y;
  int cnt = counts[b * 2 + 1];
  int base = blockIdx.x * 16;
  if (base >= cnt) return;
  int tid = threadIdx.x;
  if (tid >= 240) return;
  int pp = tid / 15, j = tid % 15;
  int gp = base + pp;
  if (gp >= cnt) return;
  int pos = poslist[(size_t)b * RESQ + gp];
  const double* p0 = t64p + (((size_t)0 * 2 + b) * RESQ + gp) * 256;
  const double* p1 = t64p + (((size_t)1 * 2 + b) * RESQ + gp) * 256;
  const double* p2 = t64p + (((size_t)2 * 2 + b) * RESQ + gp) * 256;
  const float* wr = (j < 3) ? (wcls + j * 256) : (wbbox + (j - 3) * 256);
  double acc = 0.0;
  for (int c = 0; c < 256; ++c) {
    double tv = fmax(p0[c] + p1[c] + p2[c] + (double)bias[c], 0.0);
    acc += tv * (double)wr[c];
  }
  if (j < 3) {
    obj64[(size_t)b * NANCH + pos * 3 + j] = acc + (double)bcls[j];
  } else {
    int jj = j - 3;
    int a = jj >> 2, kk = jj & 3;
    deltas64[((size_t)b * NANCH + pos * 3 + a) * 4 + kk] = acc + (double)bbbox[jj];
  }
}

// ---------------- exact top-2000 over candidates + decode ----------------
__global__ __launch_bounds__(1024) void topk_decode_k(const unsigned* __restrict__ cand,
                                                      const int* __restrict__ counts,
                                                      const double* __restrict__ obj64,
                                                      const double* __restrict__ deltas64,
                                                      double* __restrict__ boxesd,
                                                      float* __restrict__ boxesf) {
  int b = blockIdx.x;
  __shared__ unsigned long long selk[RESQ];
  __shared__ unsigned seli[RESQ];
  int tid = threadIdx.x;
  int acnt = counts[b * 2 + 0];
  for (int s = tid; s < RESQ; s += 1024) {
    if (s < acnt) {
      unsigned idx = cand[(size_t)b * RESQ + s];
      selk[s] = mapu64(obj64[(size_t)b * NANCH + idx]);
      seli[s] = idx;
    } else {
      selk[s] = 0ULL;
      seli[s] = 0xFFFFFFFFu;
    }
  }
  __syncthreads();
  for (unsigned k = 2; k <= RESQ; k <<= 1) {
    for (unsigned j = k >> 1; j > 0; j >>= 1) {
      for (int i = tid; i < RESQ; i += 1024) {
        int l = i ^ (int)j;
        if (l > i) {
          unsigned long long ka = selk[i], kb = selk[l];
          unsigned ia = seli[i], ib = seli[l];
          bool before_lb = (kb > ka) || (kb == ka && ib < ia);
          bool asc = ((i & (int)k) == 0);
          if (asc == before_lb) {
            selk[i] = kb; selk[l] = ka;
            seli[i] = ib; seli[l] = ia;
          }
        }
      }
      __syncthreads();
    }
  }
  const double ratios[3] = {0.5, 1.0, 2.0};
  for (int p = tid; p < PRE; p += 1024) {
    unsigned idx = seli[p];
    int a = (int)(idx % 3u);
    int pos = (int)(idx / 3u);
    int ypix = pos / 100, xpix = pos % 100;
    double sx = (double)(xpix * 8), sy = (double)(ypix * 8);
    double sq = sqrt(ratios[a]);
    double w2 = (64.0 / sq) * 0.5;
    double h2 = (64.0 * sq) * 0.5;
    float x1a = (float)(sx - w2), y1a = (float)(sy - h2);
    float x2a = (float)(sx + w2), y2a = (float)(sy + h2);
    double wa = (double)x2a - (double)x1a;
    double ha = (double)y2a - (double)y1a;
    double cxa = (double)x1a + 0.5 * wa, cya = (double)y1a + 0.5 * ha;
    const double* dd = deltas64 + ((size_t)b * NANCH + idx) * 4;
    double dx = dd[0], dy = dd[1];
    double dw = fmin(dd[2], CLAMPD), dh = fmin(dd[3], CLAMPD);
    double cx = dx * wa + cxa, cy = dy * ha + cya;
    double w = exp(dw) * wa, h = exp(dh) * ha;
    double bx1 = fmin(fmax(cx - 0.5 * w, 0.0), 800.0);
    double by1 = fmin(fmax(cy - 0.5 * h, 0.0), 800.0);
    double bx2 = fmin(fmax(cx + 0.5 * w, 0.0), 800.0);
    double by2 = fmin(fmax(cy + 0.5 * h, 0.0), 800.0);
    double* bo = boxesd + ((size_t)b * PRE + p) * 4;
    bo[0] = bx1; bo[1] = by1; bo[2] = bx2; bo[3] = by2;
    float* bf = boxesf + ((size_t)b * PRE + p) * 4;
    bf[0] = (float)bx1; bf[1] = (float)by1; bf[2] = (float)bx2; bf[3] = (float)by2;
  }
}

// ---------------- suppression matrix (FP64 IoU) ----------------
__global__ void supmat_k(const double* __restrict__ boxes, unsigned* __restrict__ sup) {
  int b = blockIdx.y;
  int gt = blockIdx.x * 256 + threadIdx.x;
  int i = gt >> 6, w = gt & 63;
  if (i >= PRE) return;
  const double* bb = boxes + (size_t)b * PRE * 4;
  double x1 = bb[i * 4 + 0], y1 = bb[i * 4 + 1], x2 = bb[i * 4 + 2], y2 = bb[i * 4 + 3];
  double a1 = (x2 - x1) * (y2 - y1);
  unsigned m = 0;
  int j0 = w * 32;
  for (int jj = 0; jj < 32; ++jj) {
    int j = j0 + jj;
    if (j >= PRE) break;
    if (j > i) {
      double u1 = bb[j * 4 + 0], v1 = bb[j * 4 + 1], u2 = bb[j * 4 + 2], v2 = bb[j * 4 + 3];
      double ltx = fmax(x1, u1), lty = fmax(y1, v1);
      double rbx = fmin(x2, u2), rby = fmin(y2, v2);
      double ww = fmax(rbx - ltx, 0.0), hh = fmax(rby - lty, 0.0);
      double inter = ww * hh;
      double a2 = (u2 - u1) * (v2 - v1);
      double iou = inter / (a1 + a2 - inter + 1e-9);
      if (iou > 0.7) m |= 1u << jj;
    }
  }
  sup[((size_t)b * 2048 + i) * 64 + w] = m;
}

// ---------------- sequential NMS: readlane walk + 4-wave parallel kill-OR ----------------
__global__ void nms_emit_k(const unsigned* __restrict__ sup, const float* __restrict__ boxes,
                           float* __restrict__ rois) {
  int b = blockIdx.x;
  int tid = threadIdx.x;
  int wv = tid >> 6, lane = tid & 63;
  __shared__ unsigned buf[2][4096];
  __shared__ unsigned kill_s[4][64];
  __shared__ unsigned aw_s[64];
  __shared__ unsigned sh_cm0, sh_cm1;
  __shared__ unsigned pre[64];
  __shared__ unsigned sh_m;
  const unsigned* sb = sup + (size_t)b * 2048 * 64;

  for (int i = tid; i < 4096; i += 256) buf[0][i] = sb[i];
  if (tid < 64) aw_s[tid] = (tid < 62) ? 0xFFFFFFFFu : (tid == 62 ? 0xFFFFu : 0u);
  __syncthreads();

  for (int c = 0; c < 32; ++c) {
    const unsigned* B = buf[c & 1];
    if (wv == 0) {
      unsigned rlo = B[lane * 64 + 2 * c];
      unsigned rhi = B[lane * 64 + 2 * c + 1];
      unsigned clo = __builtin_amdgcn_readfirstlane(aw_s[2 * c]);
      unsigned chi = __builtin_amdgcn_readfirstlane(aw_s[2 * c + 1]);
      unsigned long long cm = (unsigned long long)clo | ((unsigned long long)chi << 32);
      unsigned long long m = cm;
      while (m) {
        int ii = __builtin_ctzll(m);
        unsigned klo = (unsigned)__builtin_amdgcn_readlane((int)rlo, ii);
        unsigned khi = (unsigned)__builtin_amdgcn_readlane((int)rhi, ii);
        unsigned long long kd = (unsigned long long)klo | ((unsigned long long)khi << 32);
        cm &= ~kd;
        m = cm & ~((2ULL << ii) - 1ULL);
      }
      if (lane == 0) { sh_cm0 = (unsigned)cm; sh_cm1 = (unsigned)(cm >> 32); }
    } else if (c + 1 < 32) {
      for (int i = tid - 64; i < 4096; i += 192) buf[(c + 1) & 1][i] = sb[(size_t)(c + 1) * 4096 + i];
    }
    __syncthreads();
    {
      unsigned long long cm = (unsigned long long)sh_cm0 | ((unsigned long long)sh_cm1 << 32);
      unsigned k = 0;
      unsigned long long m2 = cm;
      int cnt = 0;
      while (m2) {
        int ii = __builtin_ctzll(m2);
        m2 &= m2 - 1;
        if ((cnt & 3) == wv) k |= B[ii * 64 + lane];
        ++cnt;
      }
      kill_s[wv][lane] = k;
    }
    __syncthreads();
    if (tid < 64)
      aw_s[tid] &= ~(kill_s[0][tid] | kill_s[1][tid] | kill_s[2][tid] | kill_s[3][tid]);
    __syncthreads();
  }
  if (tid == 0) {
    unsigned m = 0;
    for (int w = 0; w < 64; ++w) { pre[w] = m; m += __popc(aw_s[w]); }
    sh_m = m;
  }
  __syncthreads();
  unsigned m = sh_m;
  for (int i = tid; i < PRE; i += 256) {
    int w = i >> 5;
    unsigned word = aw_s[w];
    unsigned lower = word & ((1u << (i & 31)) - 1u);
    unsigned rank = pre[w] + __popc(lower);
    bool al = (word >> (i & 31)) & 1u;
    unsigned dst;
    if (al) {
      if (rank >= POST) continue;
      dst = rank;
    } else {
      unsigned dpos = m + ((unsigned)i - rank);
      if (dpos >= POST) continue;
      dst = dpos;
    }
    const float4 v = *(const float4*)(boxes + ((size_t)b * PRE + i) * 4);
    *(float4*)(rois + ((size_t)b * POST + dst) * 4) = v;
  }
}

// ---------------- roi align (7x7, SR=2) over NHWC f32 features -> bf16 pooled ----------------
__global__ void roi_align_k(const float* __restrict__ featT, const float* __restrict__ rois,
                            __hip_bfloat16* __restrict__ pooled) {
  __shared__ float slx[14], sly[14];
  __shared__ int sx0[14], sx1[14], sy0[14], sy1[14];
  int tid = threadIdx.x;
  int gro = blockIdx.x;
  int b = gro / POST;
  const float* r = rois + (size_t)gro * 4;
  if (tid < 14) {
    float x1 = r[0] * 0.125f, x2 = r[2] * 0.125f;
    float bw = (x2 - x1) / 7.0f;
    float k = ((float)tid + 0.5f) / 2.0f;
    float xs = fminf(fmaxf(x1 + bw * k, 0.f), 99.f);
    float x0f = floorf(xs);
    int x0i = (int)x0f;
    sx0[tid] = x0i; sx1[tid] = min(x0i + 1, 99); slx[tid] = xs - x0f;
  } else if (tid < 28) {
    int s = tid - 14;
    float y1 = r[1] * 0.125f, y2 = r[3] * 0.125f;
    float bh = (y2 - y1) / 7.0f;
    float k = ((float)s + 0.5f) / 2.0f;
    float ys = fminf(fmaxf(y1 + bh * k, 0.f), 99.f);
    float y0f = floorf(ys);
    int y0i = (int)y0f;
    sy0[s] = y0i; sy1[s] = min(y0i + 1, 99); sly[s] = ys - y0f;
  }
  __syncthreads();
  int c = tid;
  const float* fb = featT + (size_t)b * NPOS * 256 + c;
  __hip_bfloat16* outp = pooled + (size_t)gro * 12544 + (size_t)c * 49;
  for (int ph = 0; ph < 7; ++ph) {
    for (int pw = 0; pw < 7; ++pw) {
      float acc = 0.f;
#pragma unroll
      for (int sy = 0; sy < 2; ++sy) {
        int yi = ph * 2 + sy;
        int y0 = sy0[yi], y1 = sy1[yi];
        float ly = sly[yi], hy = 1.f - ly;
#pragma unroll
        for (int sx = 0; sx < 2; ++sx) {
          int xi = pw * 2 + sx;
          int x0 = sx0[xi], x1 = sx1[xi];
          float lx = slx[xi], hx = 1.f - lx;
          float v00 = fb[(size_t)(y0 * 100 + x0) * 256];
          float v01 = fb[(size_t)(y0 * 100 + x1) * 256];
          float v10 = fb[(size_t)(y1 * 100 + x0) * 256];
          float v11 = fb[(size_t)(y1 * 100 + x1) * 256];
          acc += hy * hx * v00 + hy * lx * v01 + ly * hx * v10 + ly * lx * v11;
        }
      }
      outp[ph * 7 + pw] = __float2bfloat16(acc * 0.25f);
    }
  }
}

// ---------------- weight transpose+convert: w f32[K][N] -> wt bf16[N][K] ----------------
__global__ void wt_bf16_k(const float* __restrict__ w, __hip_bfloat16* __restrict__ wt,
                          int K, int N) {
  __shared__ float tile[32][33];
  int k0 = blockIdx.x * 32, n0 = blockIdx.y * 32;
  int tx = threadIdx.x & 31, ty = threadIdx.x >> 5;
  for (int r = 0; r < 4; ++r)
    tile[ty + r * 8][tx] = w[(size_t)(k0 + ty + r * 8) * N + n0 + tx];
  __syncthreads();
  for (int r = 0; r < 4; ++r)
    wt[(size_t)(n0 + ty + r * 8) * K + k0 + tx] = __float2bfloat16(tile[tx][ty + r * 8]);
}

// ---------------- bf16 MFMA GEMM (128x128 tile; used for FC2) ----------------
__global__ __launch_bounds__(256) void gemm_bf16_k(const __hip_bfloat16* __restrict__ A,
                                                   const __hip_bfloat16* __restrict__ Bt,
                                                   const float* __restrict__ bias,
                                                   __hip_bfloat16* __restrict__ C,
                                                   int N, int K, int relu) {
  __shared__ __hip_bfloat16 As[128 * 64];
  __shared__ __hip_bfloat16 Bs[128 * 64];
  const int t = threadIdx.x;
  const int w = t >> 6;
  const int lane = t & 63;
  const int lr = lane & 15, lg = lane >> 4;
  const int wr = w >> 1, wc = w & 1;
  const int m0 = blockIdx.y * 128, n0 = blockIdx.x * 128;

  f32x4v acc[4][4];
#pragma unroll
  for (int i = 0; i < 4; ++i)
#pragma unroll
    for (int j = 0; j < 4; ++j)
#pragma unroll
      for (int r = 0; r < 4; ++r) acc[i][j][r] = 0.f;

  int srow[4], soff[4];
#pragma unroll
  for (int i = 0; i < 4; ++i) {
    int c = i * 256 + t;
    int row = c >> 3, ccd = c & 7;
    srow[i] = row;
    soff[i] = (ccd ^ (row & 7)) * 8;
  }
  int arow[4], brow[4], sk[2];
#pragma unroll
  for (int ms = 0; ms < 4; ++ms) arow[ms] = (wr * 64 + ms * 16 + lr) * 128;
#pragma unroll
  for (int ns = 0; ns < 4; ++ns) brow[ns] = (wc * 64 + ns * 16 + lr) * 128;
#pragma unroll
  for (int kk = 0; kk < 2; ++kk) sk[kk] = (((kk * 4 + lg) ^ (lr & 7)) * 16);

  for (int k0 = 0; k0 < K; k0 += 64) {
    __syncthreads();
#pragma unroll
    for (int i = 0; i < 4; ++i) {
      const __hip_bfloat16* ga = A + (size_t)(m0 + srow[i]) * K + k0 + soff[i];
      async_load16(ga, (char*)As + ((i * 256 + w * 64) * 16));
    }
#pragma unroll
    for (int i = 0; i < 4; ++i) {
      const __hip_bfloat16* gb = Bt + (size_t)(n0 + srow[i]) * K + k0 + soff[i];
      async_load16(gb, (char*)Bs + ((i * 256 + w * 64) * 16));
    }
    __syncthreads();

    bf16x8v af[2][4], bf[2][4];
#pragma unroll
    for (int kk = 0; kk < 2; ++kk) {
#pragma unroll
      for (int ms = 0; ms < 4; ++ms)
        af[kk][ms] = *(const bf16x8v*)((const char*)As + arow[ms] + sk[kk]);
#pragma unroll
      for (int ns = 0; ns < 4; ++ns)
        bf[kk][ns] = *(const bf16x8v*)((const char*)Bs + brow[ns] + sk[kk]);
    }
#pragma unroll
    for (int ms = 0; ms < 4; ++ms)
#pragma unroll
      for (int ns = 0; ns < 4; ++ns) {
        acc[ms][ns] = __builtin_amdgcn_mfma_f32_16x16x32_bf16(af[0][ms], bf[0][ns], acc[ms][ns], 0, 0, 0);
        acc[ms][ns] = __builtin_amdgcn_mfma_f32_16x16x32_bf16(af[1][ms], bf[1][ns], acc[ms][ns], 0, 0, 0);
      }
  }

#pragma unroll
  for (int ms = 0; ms < 4; ++ms) {
    int gm = m0 + wr * 64 + ms * 16 + lg * 4;
#pragma unroll
    for (int ns = 0; ns < 4; ++ns) {
      int gn = n0 + wc * 64 + ns * 16 + lr;
      float bv = bias[gn];
#pragma unroll
      for (int r = 0; r < 4; ++r) {
        float v = acc[ms][ns][r] + bv;
        if (relu) v = fmaxf(v, 0.f);
        C[(size_t)(gm + r) * N + gn] = __float2bfloat16(v);
      }
    }
  }
}

// ---------------- FC1 K-split GEMM: part[ks][m][n] (fp32, no bias) ----------------
#define FC1K 12544
#define FC1KS 2
#define FC1KSEG (FC1K / FC1KS)
__global__ __launch_bounds__(256) void gemm_part_k(const __hip_bfloat16* __restrict__ A,
                                                   const __hip_bfloat16* __restrict__ Bt,
                                                   float* __restrict__ part) {
  __shared__ __hip_bfloat16 As[128 * 64];
  __shared__ __hip_bfloat16 Bs[64 * 64];
  const int t = threadIdx.x;
  const int w = t >> 6;
  const int lane = t & 63;
  const int lr = lane & 15, lg = lane >> 4;
  const int wr = w >> 1, wc = w & 1;
  const int m0 = blockIdx.y * 128, n0 = blockIdx.x * 64;
  const int ks = blockIdx.z;
  const int kbase = ks * FC1KSEG;

  f32x4v acc[4][2];
#pragma unroll
  for (int i = 0; i < 4; ++i)
#pragma unroll
    for (int j = 0; j < 2; ++j)
#pragma unroll
      for (int r = 0; r < 4; ++r) acc[i][j][r] = 0.f;

  int srow[4], soff[4];
#pragma unroll
  for (int i = 0; i < 4; ++i) {
    int c = i * 256 + t;
    int row = c >> 3, ccd = c & 7;
    srow[i] = row;
    soff[i] = (ccd ^ (row & 7)) * 8;
  }
  int arow[4], brow[2], sk[2];
#pragma unroll
  for (int ms = 0; ms < 4; ++ms) arow[ms] = (wr * 64 + ms * 16 + lr) * 128;
#pragma unroll
  for (int ns = 0; ns < 2; ++ns) brow[ns] = (wc * 32 + ns * 16 + lr) * 128;
#pragma unroll
  for (int kk = 0; kk < 2; ++kk) sk[kk] = (((kk * 4 + lg) ^ (lr & 7)) * 16);

  for (int k0 = 0; k0 < FC1KSEG; k0 += 64) {
    __syncthreads();
#pragma unroll
    for (int i = 0; i < 4; ++i) {
      const __hip_bfloat16* ga = A + (size_t)(m0 + srow[i]) * FC1K + kbase + k0 + soff[i];
      async_load16(ga, (char*)As + ((i * 256 + w * 64) * 16));
    }
#pragma unroll
    for (int i = 0; i < 2; ++i) {
      const __hip_bfloat16* gb = Bt + (size_t)(n0 + srow[i]) * FC1K + kbase + k0 + soff[i];
      async_load16(gb, (char*)Bs + ((i * 256 + w * 64) * 16));
    }
    __syncthreads();

    bf16x8v af[2][4], bf[2][2];
#pragma unroll
    for (int kk = 0; kk < 2; ++kk) {
#pragma unroll
      for (int ms = 0; ms < 4; ++ms)
        af[kk][ms] = *(const bf16x8v*)((const char*)As + arow[ms] + sk[kk]);
#pragma unroll
      for (int ns = 0; ns < 2; ++ns)
        bf[kk][ns] = *(const bf16x8v*)((const char*)Bs + brow[ns] + sk[kk]);
    }
#pragma unroll
    for (int ms = 0; ms < 4; ++ms)
#pragma unroll
      for (int ns = 0; ns < 2; ++ns) {
        acc[ms][ns] = __builtin_amdgcn_mfma_f32_16x16x32_bf16(af[0][ms], bf[0][ns], acc[ms][ns], 0, 0, 0);
        acc[ms][ns] = __builtin_amdgcn_mfma_f32_16x16x32_bf16(af[1][ms], bf[1][ns], acc[ms][ns], 0, 0, 0);
      }
  }

  float* pb = part + (size_t)ks * 2048 * 1024;
#pragma unroll
  for (int ms = 0; ms < 4; ++ms) {
    int gm = m0 + wr * 64 + ms * 16 + lg * 4;
#pragma unroll
    for (int ns = 0; ns < 2; ++ns) {
      int gn = n0 + wc * 32 + ns * 16 + lr;
#pragma unroll
      for (int r = 0; r < 4; ++r)
        pb[(size_t)(gm + r) * 1024 + gn] = acc[ms][ns][r];
    }
  }
}

// ---------------- reduce partials: x1 = bf16(relu(p0+p1+bias)) ----------------
__global__ void reduce_bias_relu_k(const float* __restrict__ part, const float* __restrict__ bias,
                                   __hip_bfloat16* __restrict__ x1) {
  int i4 = blockIdx.x * 256 + threadIdx.x;
  if (i4 >= 524288) return;
  const float4 a = ((const float4*)part)[i4];
  const float4 b = ((const float4*)part)[524288 + i4];
  const float4 bv = ((const float4*)bias)[i4 & 255];
  float v0 = fmaxf(a.x + b.x + bv.x, 0.f);
  float v1 = fmaxf(a.y + b.y + bv.y, 0.f);
  float v2 = fmaxf(a.z + b.z + bv.z, 0.f);
  float v3 = fmaxf(a.w + b.w + bv.w, 0.f);
  __hip_bfloat16* o = x1 + (size_t)i4 * 4;
  o[0] = __float2bfloat16(v0);
  o[1] = __float2bfloat16(v1);
  o[2] = __float2bfloat16(v2);
  o[3] = __float2bfloat16(v3);
}

// ---------------- final heads ----------------
__global__ void final_heads_k(const __hip_bfloat16* __restrict__ x2,
                              const float* __restrict__ cls_w, const float* __restrict__ cls_b,
                              const float* __restrict__ reg_w, const float* __restrict__ reg_b,
                              float* __restrict__ out) {
  __shared__ float wl[1024][10];
  int tid = threadIdx.x;
  for (int i = tid; i < 1024 * 10; i += 256) {
    int k = i / 10, n = i % 10;
    wl[k][n] = (n < 2) ? cls_w[k * 2 + n] : reg_w[k * 8 + (n - 2)];
  }
  __syncthreads();
  int gt = blockIdx.x * 256 + tid;
  if (gt >= 2 * POST * 10) return;
  int mg = gt / 10, n = gt % 10;
  const __hip_bfloat16* xr = x2 + (size_t)mg * 1024;
  float acc = 0.f;
  for (int k = 0; k < 1024; ++k) acc += __bfloat162float(xr[k]) * wl[k][n];
  acc += (n < 2) ? cls_b[n] : reg_b[n - 2];
  out[(size_t)mg * 10 + n] = acc;
}

extern "C" void kernel_launch(void* const* d_in, const int* in_sizes, int n_in,
                              void* d_out, int out_size, void* d_ws, size_t ws_size,
                              hipStream_t stream) {
  const float* features   = (const float*)d_in[0];
  const float* rpn_conv_w = (const float*)d_in[1];
  const float* rpn_conv_b = (const float*)d_in[2];
  const float* rpn_cls_w  = (const float*)d_in[3];
  const float* rpn_cls_b  = (const float*)d_in[4];
  const float* rpn_bbox_w = (const float*)d_in[5];
  const float* rpn_bbox_b = (const float*)d_in[6];
  const float* fc1_w = (const float*)d_in[7];
  const float* fc1_b = (const float*)d_in[8];
  const float* fc2_w = (const float*)d_in[9];
  const float* fc2_b = (const float*)d_in[10];
  const float* cls_w = (const float*)d_in[11];
  const float* cls_b = (const float*)d_in[12];
  const float* reg_w = (const float*)d_in[13];
  const float* reg_b = (const float*)d_in[14];
  float* out = (float*)d_out;

  char* ws = (char*)d_ws;
  size_t off = 0;
  auto alloc = [&](size_t bytes) -> void* {
    off = (off + 255) & ~(size_t)255;
    void* p = ws + off;
    off += bytes;
    return p;
  };
  // persistent buffers
  float* featT = (float*)alloc((size_t)2 * NPOS * 256 * 4);
  float* rois  = (float*)alloc((size_t)2 * POST * 4 * 4);
  __hip_bfloat16* w1t = (__hip_bfloat16*)alloc((size_t)1024 * 12544 * 2);
  __hip_bfloat16* w2t = (__hip_bfloat16*)alloc((size_t)1024 * 1024 * 2);
  __hip_bfloat16* x1  = (__hip_bfloat16*)alloc((size_t)2048 * 1024 * 2);
  __hip_bfloat16* x2  = (__hip_bfloat16*)alloc((size_t)2048 * 1024 * 2);
  // aliased region: RPN intermediates (dead after nms), then pooled + fc1 partials
  off = (off + 255) & ~(size_t)255;
  size_t region = off;
  double*   wT64r    = (double*)alloc((size_t)589824 * 8);
  __hip_bfloat16* fpadB = (__hip_bfloat16*)alloc((size_t)2 * FPH * FPW * 256 * 2);
  __hip_bfloat16* wBt   = (__hip_bfloat16*)alloc((size_t)589824 * 2);
  // union: {t32 (20.5MB) + objf (0.24MB)} before select_k  |  t64p (50.3MB) after
  off = (off + 255) & ~(size_t)255;
  size_t uni = off;
  float*  t32  = (float*)(ws + uni);
  float*  objf = (float*)(ws + uni + (((size_t)2 * NPOS * 256 * 4 + 255) & ~(size_t)255));
  double* t64p = (double*)(ws + uni);
  size_t uni_sz = (size_t)3 * 2 * RESQ * 256 * 8;   // 50.3 MB > t32+objf
  off = uni + uni_sz;
  double*   obj64    = (double*)alloc((size_t)2 * NANCH * 8);
  double*   deltas64 = (double*)alloc((size_t)2 * NANCH * 4 * 8);
  double*   boxesd   = (double*)alloc((size_t)2 * PRE * 4 * 8);
  float*    boxesf   = (float*)alloc((size_t)2 * PRE * 4 * 4);
  unsigned* sup      = (unsigned*)alloc((size_t)2 * 2048 * 64 * 4);
  unsigned* cand     = (unsigned*)alloc((size_t)2 * RESQ * 4);
  int*      poslist  = (int*)alloc((size_t)2 * RESQ * 4);
  int*      counts   = (int*)alloc(64);
  // pooled + fc1 partials alias the whole RPN region (everything above is dead post-nms)
  __hip_bfloat16* pooled = (__hip_bfloat16*)(ws + region);
  size_t pooled_sz = (size_t)2048 * 12544 * 2;                 // 51.4 MB
  float* fc1part = (float*)(ws + region + ((pooled_sz + 255) & ~(size_t)255));
  size_t part_end = region + ((pooled_sz + 255) & ~(size_t)255) + (size_t)FC1KS * 2048 * 1024 * 4;
  if (off < part_end) off = part_end;
  (void)ws_size; (void)in_sizes; (void)n_in; (void)out_size;

  repack_w_k<<<2304, 256, 0, stream>>>(rpn_conv_w, wT64r);
  wbt_k<<<2304, 256, 0, stream>>>(rpn_conv_w, wBt);
  transpose_feat_k<<<dim3(313, 8, 2), 256, 0, stream>>>(features, featT);
  fpad_zero_k<<<3366, 256, 0, stream>>>(fpadB);
  fpad_fill_k<<<dim3(313, 8, 2), 256, 0, stream>>>(features, fpadB);
  conv_mfma_k<<<dim3(2, 200), 256, 0, stream>>>(fpadB, wBt, rpn_conv_b, t32);
  rpn_obj_k<<<79, 256, 0, stream>>>(t32, rpn_cls_w, rpn_cls_b, objf);
  select_k<<<2, 1024, 0, stream>>>(objf, cand, poslist, counts, 8e-3f);
  rescore_t3_k<<<dim3(4, RESQ / 64, 6), 256, 0, stream>>>(featT, wT64r, poslist, counts, t64p);
  rescore_heads_k<<<dim3(RESQ / 16, 2), 256, 0, stream>>>(t64p, rpn_conv_b, poslist, counts,
                                                          rpn_cls_w, rpn_cls_b, rpn_bbox_w,
                                                          rpn_bbox_b, obj64, deltas64);
  topk_decode_k<<<2, 1024, 0, stream>>>(cand, counts, obj64, deltas64, boxesd, boxesf);
  supmat_k<<<dim3(512, 2), 256, 0, stream>>>(boxesd, sup);
  nms_emit_k<<<2, 256, 0, stream>>>(sup, boxesf, rois);
  wt_bf16_k<<<dim3(392, 32), 256, 0, stream>>>(fc1_w, w1t, 12544, 1024);
  wt_bf16_k<<<dim3(32, 32), 256, 0, stream>>>(fc2_w, w2t, 1024, 1024);
  roi_align_k<<<2 * POST, 256, 0, stream>>>(featT, rois, pooled);
  gemm_part_k<<<dim3(16, 16, FC1KS), 256, 0, stream>>>(pooled, w1t, fc1part);
  reduce_bias_relu_k<<<2048, 256, 0, stream>>>(fc1part, fc1_b, x1);
  gemm_bf16_k<<<dim3(8, 16), 256, 0, stream>>>(x1, w2t, fc2_b, x2, 1024, 1024, 1);
  final_heads_k<<<79, 256, 0, stream>>>(x2, cls_w, cls_b, reg_w, reg_b, out);
}

// Round 15
// 960.706 us; speedup vs baseline: 1.3674x; 1.3674x over previous
//
#include <hip/hip_runtime.h>
#include <hip/hip_bf16.h>
#include <math.h>

#define NPOS 10000
#define NANCH 30000
#define PRE 2000
#define POST 1000
#define RESQ 4096
#define CLAMPD 4.135166556742356
#define FPH 102
#define FPW 132

typedef __attribute__((ext_vector_type(8))) short bf16x8v;
typedef __attribute__((ext_vector_type(4))) float f32x4v;

__device__ __forceinline__ unsigned long long mapu64(double f) {
  unsigned long long b = (unsigned long long)__double_as_longlong(f);
  return (b & 0x8000000000000000ULL) ? ~b : (b | 0x8000000000000000ULL);
}
__device__ __forceinline__ unsigned mapu32(float f) {
  unsigned b = __float_as_uint(f);
  return (b & 0x80000000u) ? ~b : (b | 0x80000000u);
}

__device__ __forceinline__ void async_load16(const void* g, void* l) {
  __builtin_amdgcn_global_load_lds((const __attribute__((address_space(1))) void*)g,
                                   (__attribute__((address_space(3))) void*)l, 16, 0, 0);
}

// ---------------- conv weights: w[co][ci][tap] (f32) -> wT64r[tap][ci][co] (f64) ----------------
__global__ void repack_w_k(const float* __restrict__ w, double* __restrict__ wT64r) {
  int tid = blockIdx.x * 256 + threadIdx.x;
  if (tid >= 589824) return;
  int co = tid / 2304;
  int rem = tid % 2304;        // ci*9 + tap
  int ci = rem / 9, tap = rem % 9;
  wT64r[((size_t)tap * 256 + ci) * 256 + co] = (double)w[tid];
}

// ---------------- conv weights: -> wBt[tap][co][ci] bf16 ----------------
__global__ void wbt_k(const float* __restrict__ w, __hip_bfloat16* __restrict__ wBt) {
  int i = blockIdx.x * 256 + threadIdx.x;
  if (i >= 589824) return;
  int tap = i >> 16;
  int co = (i >> 8) & 255;
  int ci = i & 255;
  wBt[i] = __float2bfloat16(w[(co * 256 + ci) * 9 + tap]);
}

// ---------------- features NCHW -> NHWC (featT[b][pos][c], f32) ----------------
__global__ void transpose_feat_k(const float* __restrict__ feat, float* __restrict__ featT) {
  __shared__ float tile[32][33];
  int b = blockIdx.z;
  int c0 = blockIdx.y * 32;
  int p0 = blockIdx.x * 32;
  int tx = threadIdx.x & 31, ty = threadIdx.x >> 5;
  for (int r = 0; r < 4; ++r) {
    int c = c0 + ty + r * 8, p = p0 + tx;
    tile[ty + r * 8][tx] = (p < NPOS) ? feat[((size_t)b * 256 + c) * NPOS + p] : 0.f;
  }
  __syncthreads();
  for (int r = 0; r < 4; ++r) {
    int p = p0 + ty + r * 8, c = c0 + tx;
    if (p < NPOS) featT[((size_t)b * NPOS + p) * 256 + c] = tile[tx][ty + r * 8];
  }
}

// ---------------- zero fpadB ----------------
__global__ void fpad_zero_k(__hip_bfloat16* __restrict__ f) {
  size_t i = (size_t)blockIdx.x * 256 + threadIdx.x;
  uint4 z = {0, 0, 0, 0};
  ((uint4*)f)[i] = z;
}

// ---------------- fill fpadB[b][y+1][x+1][c] = bf16(feat[b][c][y*100+x]) ----------------
__global__ void fpad_fill_k(const float* __restrict__ feat, __hip_bfloat16* __restrict__ fpadB) {
  __shared__ float tile[32][33];
  int b = blockIdx.z;
  int c0 = blockIdx.y * 32;
  int p0 = blockIdx.x * 32;
  int tx = threadIdx.x & 31, ty = threadIdx.x >> 5;
  for (int r = 0; r < 4; ++r) {
    int c = c0 + ty + r * 8, p = p0 + tx;
    tile[ty + r * 8][tx] = (p < NPOS) ? feat[((size_t)b * 256 + c) * NPOS + p] : 0.f;
  }
  __syncthreads();
  for (int r = 0; r < 4; ++r) {
    int p = p0 + ty + r * 8, c = c0 + tx;
    if (p < NPOS) {
      int y = p / 100, x = p % 100;
      fpadB[(((size_t)b * FPH + y + 1) * FPW + (x + 1)) * 256 + c] =
          __float2bfloat16(tile[tx][ty + r * 8]);
    }
  }
}

// ---------------- 3x3 conv via bf16 MFMA ----------------
__global__ __launch_bounds__(256) void conv_mfma_k(const __hip_bfloat16* __restrict__ fpadB,
                                                   const __hip_bfloat16* __restrict__ wBt,
                                                   const float* __restrict__ bias,
                                                   float* __restrict__ t32) {
  __shared__ __hip_bfloat16 As[128 * 64];
  __shared__ __hip_bfloat16 Bs[128 * 64];
  const int t = threadIdx.x;
  const int wv = t >> 6;
  const int lane = t & 63;
  const int lr = lane & 15, lg = lane >> 4;
  const int wr = wv >> 1, wc = wv & 1;
  const int co0 = blockIdx.x * 128;
  const int mt = blockIdx.y;
  const int img = mt / 100;
  const int rem = mt % 100;
  const int y0 = (rem / 4) * 4, x0 = (rem % 4) * 32;

  f32x4v acc[4][4];
#pragma unroll
  for (int i = 0; i < 4; ++i)
#pragma unroll
    for (int j = 0; j < 4; ++j)
#pragma unroll
      for (int r = 0; r < 4; ++r) acc[i][j][r] = 0.f;

  int srow[4], sseg[4];
#pragma unroll
  for (int i = 0; i < 4; ++i) {
    int c = i * 256 + t;
    srow[i] = c >> 3;
    sseg[i] = (c & 7) ^ (srow[i] & 7);
  }
  int arow[4], brow[4], sk[2];
#pragma unroll
  for (int ms = 0; ms < 4; ++ms) arow[ms] = (wr * 64 + ms * 16 + lr) * 128;
#pragma unroll
  for (int ns = 0; ns < 4; ++ns) brow[ns] = (wc * 64 + ns * 16 + lr) * 128;
#pragma unroll
  for (int kk = 0; kk < 2; ++kk) sk[kk] = (((kk * 4 + lg) ^ (lr & 7)) * 16);

  for (int chunk = 0; chunk < 36; ++chunk) {
    int tap = chunk >> 2;
    int ci0 = (chunk & 3) * 64;
    int dy = tap / 3, dx = tap % 3;
    __syncthreads();
#pragma unroll
    for (int i = 0; i < 4; ++i) {
      int r = srow[i];
      int py = y0 + (r >> 5) + dy, px = x0 + (r & 31) + dx;
      const __hip_bfloat16* ga =
          fpadB + ((((size_t)img * FPH + py) * FPW + px) << 8) + ci0 + sseg[i] * 8;
      async_load16(ga, (char*)As + ((i * 256 + wv * 64) * 16));
    }
#pragma unroll
    for (int i = 0; i < 4; ++i) {
      int r = srow[i];
      const __hip_bfloat16* gb =
          wBt + ((size_t)(tap * 256 + co0 + r) << 8) + ci0 + sseg[i] * 8;
      async_load16(gb, (char*)Bs + ((i * 256 + wv * 64) * 16));
    }
    __syncthreads();

    bf16x8v af[2][4], bf[2][4];
#pragma unroll
    for (int kk = 0; kk < 2; ++kk) {
#pragma unroll
      for (int ms = 0; ms < 4; ++ms)
        af[kk][ms] = *(const bf16x8v*)((const char*)As + arow[ms] + sk[kk]);
#pragma unroll
      for (int ns = 0; ns < 4; ++ns)
        bf[kk][ns] = *(const bf16x8v*)((const char*)Bs + brow[ns] + sk[kk]);
    }
#pragma unroll
    for (int ms = 0; ms < 4; ++ms)
#pragma unroll
      for (int ns = 0; ns < 4; ++ns) {
        acc[ms][ns] = __builtin_amdgcn_mfma_f32_16x16x32_bf16(af[0][ms], bf[0][ns], acc[ms][ns], 0, 0, 0);
        acc[ms][ns] = __builtin_amdgcn_mfma_f32_16x16x32_bf16(af[1][ms], bf[1][ns], acc[ms][ns], 0, 0, 0);
      }
  }

#pragma unroll
  for (int ms = 0; ms < 4; ++ms) {
    int mbase = wr * 64 + ms * 16 + lg * 4;
#pragma unroll
    for (int ns = 0; ns < 4; ++ns) {
      int gn = co0 + wc * 64 + ns * 16 + lr;
      float bv = bias[gn];
#pragma unroll
      for (int r = 0; r < 4; ++r) {
        int m = mbase + r;
        int y = y0 + (m >> 5), x = x0 + (m & 31);
        if (x < 100)
          t32[((size_t)(img * NPOS + y * 100 + x)) * 256 + gn] = fmaxf(acc[ms][ns][r] + bv, 0.f);
      }
    }
  }
}

// ---------------- approximate obj head (f32) from t32[pos][c] ----------------
__global__ void rpn_obj_k(const float* __restrict__ t32, const float* __restrict__ wcls,
                          const float* __restrict__ bcls, float* __restrict__ obj) {
  __shared__ float wl[3][256];
  int tid = threadIdx.x;
  for (int i = tid; i < 768; i += 256) wl[i / 256][i % 256] = wcls[i];
  __syncthreads();
  int gp = blockIdx.x * 256 + tid;
  if (gp >= 2 * NPOS) return;
  const float* tr = t32 + (size_t)gp * 256;
  float a0 = 0.f, a1 = 0.f, a2 = 0.f;
  for (int c = 0; c < 256; c += 4) {
    float4 v = *(const float4*)&tr[c];
    a0 += v.x * wl[0][c] + v.y * wl[0][c + 1] + v.z * wl[0][c + 2] + v.w * wl[0][c + 3];
    a1 += v.x * wl[1][c] + v.y * wl[1][c + 1] + v.z * wl[1][c + 2] + v.w * wl[1][c + 3];
    a2 += v.x * wl[2][c] + v.y * wl[2][c + 1] + v.z * wl[2][c + 2] + v.w * wl[2][c + 3];
  }
  int b = gp / NPOS, lp = gp % NPOS;
  obj[(size_t)b * NANCH + lp * 3 + 0] = a0 + bcls[0];
  obj[(size_t)b * NANCH + lp * 3 + 1] = a1 + bcls[1];
  obj[(size_t)b * NANCH + lp * 3 + 2] = a2 + bcls[2];
}

// ---------------- candidate select: f32 radix-select T(2000th) + band ----------------
__global__ __launch_bounds__(1024) void select_k(const float* __restrict__ obj,
                                                 unsigned* __restrict__ cand,
                                                 int* __restrict__ poslist,
                                                 int* __restrict__ counts, float delta) {
  int b = blockIdx.x;
  __shared__ unsigned hist[16][256];
  __shared__ unsigned posbm[320];
  __shared__ unsigned sh_prefix, sh_rem;
  __shared__ int sh_ac, sh_pc;
  int tid = threadIdx.x;
  int wid = tid >> 6;
  const float* ob = obj + (size_t)b * NANCH;

  if (tid == 0) { sh_prefix = 0; sh_rem = PRE; sh_ac = 0; sh_pc = 0; }
  for (int i = tid; i < 320; i += 1024) posbm[i] = 0;
  for (int shift = 24; shift >= 0; shift -= 8) {
    for (int i = tid; i < 16 * 256; i += 1024) ((unsigned*)hist)[i] = 0;
    __syncthreads();
    unsigned pref = sh_prefix;
    unsigned himask = (shift == 24) ? 0u : (0xFFFFFFFFu << (shift + 8));
    for (int i = tid; i < NANCH; i += 1024) {
      unsigned u = mapu32(ob[i]);
      if ((u & himask) == pref) atomicAdd(&hist[wid][(u >> shift) & 255], 1u);
    }
    __syncthreads();
    if (tid < 256) {
      unsigned s = hist[0][tid];
      for (int w = 1; w < 16; ++w) s += hist[w][tid];
      hist[0][tid] = s;
    }
    __syncthreads();
    if (tid == 0) {
      unsigned rem = sh_rem, pfx = sh_prefix;
      for (int bb = 255; bb >= 0; --bb) {
        unsigned c = hist[0][bb];
        if (rem > c) rem -= c;
        else { pfx |= ((unsigned)bb) << shift; break; }
      }
      sh_prefix = pfx; sh_rem = rem;
    }
    __syncthreads();
  }
  unsigned T = sh_prefix;
  float Tval = __uint_as_float((T & 0x80000000u) ? (T & 0x7FFFFFFFu) : ~T);
  float thr = Tval - delta;
  for (int i = tid; i < NANCH; i += 1024) {
    if (ob[i] >= thr) {
      int p = atomicAdd(&sh_ac, 1);
      if (p < RESQ) cand[(size_t)b * RESQ + p] = (unsigned)i;
      int pos = i / 3;
      atomicOr(&posbm[pos >> 5], 1u << (pos & 31));
    }
  }
  __syncthreads();
  for (int w = tid; w < 313; w += 1024) {
    unsigned word = posbm[w];
    while (word) {
      int bit = __builtin_ctz(word);
      word &= word - 1;
      int q = atomicAdd(&sh_pc, 1);
      if (q < RESQ) poslist[(size_t)b * RESQ + q] = w * 32 + bit;
    }
  }
  __syncthreads();
  if (tid == 0) {
    counts[b * 2 + 0] = min(sh_ac, RESQ);
    counts[b * 2 + 1] = min(sh_pc, RESQ);
  }
}

// ---------------- f64 rescore, 3-way tap-split GEMM partials ----------------
// z = img*3 + tapgroup; block = 64 pos x 64 co; thread = 4 pos x 4 co (co strided 16).
// A staged in LDS as FLOAT, stride 65 (write <=2-way, scalar reads conflict-free);
// f32->f64 convert at read (exact). B staged as double, stride 66 (<=2-way).
// FMA order identical to the R13 version -> t64p bit-identical.
__global__ __launch_bounds__(256) void rescore_t3_k(const float* __restrict__ featT,
                                                    const double* __restrict__ wT64r,
                                                    const int* __restrict__ poslist,
                                                    const int* __restrict__ counts,
                                                    double* __restrict__ t64p) {
  int z = blockIdx.z;
  int b = z / 3, tg = z % 3;
  int cnt = counts[b * 2 + 1];
  int mbase = blockIdx.y * 64;
  if (mbase >= cnt) return;
  int co0 = blockIdx.x * 64;
  __shared__ float Asf[32][65];
  __shared__ double Bs[32][66];
  __shared__ int sgy[64], sgx[64];
  int tid = threadIdx.x;
  int tx = tid & 15;           // co lane: co = co0 + tx + 16j
  int ty = tid >> 4;           // pos quad: p = ty*4 + {0..3}
  if (tid < 64) {
    int q = mbase + tid;
    int pos = poslist[(size_t)b * RESQ + (q < cnt ? q : (cnt - 1))];
    sgy[tid] = pos / 100;
    sgx[tid] = pos % 100;
  }
  __syncthreads();
  const float* fb = featT + (size_t)b * NPOS * 256;

  double acc[4][4] = {};
  int ar = tid >> 2, aq = tid & 3;
  int bk = tid >> 3, bq = tid & 7;

  for (int tt = 0; tt < 3; ++tt) {
    int tap = tg * 3 + tt;
    int dy = tap / 3 - 1, dx = tap % 3 - 1;
    for (int cc = 0; cc < 8; ++cc) {
      int ci0 = cc * 32;
      __syncthreads();
      {
        int gy = sgy[ar] + dy, gx = sgx[ar] + dx;
        float4 v0 = {0.f, 0.f, 0.f, 0.f}, v1 = {0.f, 0.f, 0.f, 0.f};
        if (gy >= 0 && gy < 100 && gx >= 0 && gx < 100) {
          const float* fp = &fb[(size_t)(gy * 100 + gx) * 256 + ci0 + aq * 8];
          v0 = *(const float4*)fp;
          v1 = *(const float4*)(fp + 4);
        }
        Asf[aq * 8 + 0][ar] = v0.x;
        Asf[aq * 8 + 1][ar] = v0.y;
        Asf[aq * 8 + 2][ar] = v0.z;
        Asf[aq * 8 + 3][ar] = v0.w;
        Asf[aq * 8 + 4][ar] = v1.x;
        Asf[aq * 8 + 5][ar] = v1.y;
        Asf[aq * 8 + 6][ar] = v1.z;
        Asf[aq * 8 + 7][ar] = v1.w;
      }
      {
        const double* gw = wT64r + ((size_t)(tap * 256 + ci0 + bk)) * 256 + co0 + bq * 8;
#pragma unroll
        for (int i = 0; i < 4; ++i)
          *(double2*)&Bs[bk][bq * 8 + i * 2] = *(const double2*)(gw + i * 2);
      }
      __syncthreads();
#pragma unroll
      for (int kk = 0; kk < 32; ++kk) {
        double a0 = (double)Asf[kk][ty * 4 + 0];
        double a1 = (double)Asf[kk][ty * 4 + 1];
        double a2 = (double)Asf[kk][ty * 4 + 2];
        double a3 = (double)Asf[kk][ty * 4 + 3];
        double b0 = Bs[kk][tx];
        double b1 = Bs[kk][tx + 16];
        double b2 = Bs[kk][tx + 32];
        double b3 = Bs[kk][tx + 48];
        acc[0][0] += a0 * b0; acc[0][1] += a0 * b1;
        acc[0][2] += a0 * b2; acc[0][3] += a0 * b3;
        acc[1][0] += a1 * b0; acc[1][1] += a1 * b1;
        acc[1][2] += a1 * b2; acc[1][3] += a1 * b3;
        acc[2][0] += a2 * b0; acc[2][1] += a2 * b1;
        acc[2][2] += a2 * b2; acc[2][3] += a2 * b3;
        acc[3][0] += a3 * b0; acc[3][1] += a3 * b1;
        acc[3][2] += a3 * b2; acc[3][3] += a3 * b3;
      }
    }
  }
#pragma unroll
  for (int p = 0; p < 4; ++p) {
    int gp = mbase + ty * 4 + p;
    if (gp >= cnt) continue;
    double* outp = t64p + (((size_t)tg * 2 + b) * RESQ + gp) * 256 + co0;
#pragma unroll
    for (int j = 0; j < 4; ++j) outp[tx + 16 * j] = acc[p][j];
  }
}

// ---------------- f64 heads: t = relu(p0+p1+p2+bias); obj/deltas dots ----------------
__global__ __launch_bounds__(256) void rescore_heads_k(const double* __restrict__ t64p,
                                                       const float* __restrict__ bias,
                                                       const int* __restrict__ poslist,
                                                       const int* __restrict__ counts,
                                                       const float* __restrict__ wcls,
                                                       const float* __restrict__ bcls,
                                                       const float* __restrict__ wbbox,
                                                       const float* __restrict__ bbbox,
                                                       double* __restrict__ obj64,
                                                       double* __restrict__ deltas64) {
  int b = blockIdx.y;
  int cnt = counts[b * 2 + 1];
  int base = blockIdx.x * 16;
  if (base >= cnt) return;
  int tid = threadIdx.x;
  if (tid >= 240) return;
  int pp = tid / 15, j = tid % 15;
  int gp = base + pp;
  if (gp >= cnt) return;
  int pos = poslist[(size_t)b * RESQ + gp];
  const double* p0 = t64p + (((size_t)0 * 2 + b) * RESQ + gp) * 256;
  const double* p1 = t64p + (((size_t)1 * 2 + b) * RESQ + gp) * 256;
  const double* p2 = t64p + (((size_t)2 * 2 + b) * RESQ + gp) * 256;
  const float* wr = (j < 3) ? (wcls + j * 256) : (wbbox + (j - 3) * 256);
  double acc = 0.0;
  for (int c = 0; c < 256; ++c) {
    double tv = fmax(p0[c] + p1[c] + p2[c] + (double)bias[c], 0.0);
    acc += tv * (double)wr[c];
  }
  if (j < 3) {
    obj64[(size_t)b * NANCH + pos * 3 + j] = acc + (double)bcls[j];
  } else {
    int jj = j - 3;
    int a = jj >> 2, kk = jj & 3;
    deltas64[((size_t)b * NANCH + pos * 3 + a) * 4 + kk] = acc + (double)bbbox[jj];
  }
}

// ---------------- exact top-2000 over candidates + decode ----------------
__global__ __launch_bounds__(1024) void topk_decode_k(const unsigned* __restrict__ cand,
                                                      const int* __restrict__ counts,
                                                      const double* __restrict__ obj64,
                                                      const double* __restrict__ deltas64,
                                                      double* __restrict__ boxesd,
                                                      float* __restrict__ boxesf) {
  int b = blockIdx.x;
  __shared__ unsigned long long selk[RESQ];
  __shared__ unsigned seli[RESQ];
  int tid = threadIdx.x;
  int acnt = counts[b * 2 + 0];
  for (int s = tid; s < RESQ; s += 1024) {
    if (s < acnt) {
      unsigned idx = cand[(size_t)b * RESQ + s];
      selk[s] = mapu64(obj64[(size_t)b * NANCH + idx]);
      seli[s] = idx;
    } else {
      selk[s] = 0ULL;
      seli[s] = 0xFFFFFFFFu;
    }
  }
  __syncthreads();
  for (unsigned k = 2; k <= RESQ; k <<= 1) {
    for (unsigned j = k >> 1; j > 0; j >>= 1) {
      for (int i = tid; i < RESQ; i += 1024) {
        int l = i ^ (int)j;
        if (l > i) {
          unsigned long long ka = selk[i], kb = selk[l];
          unsigned ia = seli[i], ib = seli[l];
          bool before_lb = (kb > ka) || (kb == ka && ib < ia);
          bool asc = ((i & (int)k) == 0);
          if (asc == before_lb) {
            selk[i] = kb; selk[l] = ka;
            seli[i] = ib; seli[l] = ia;
          }
        }
      }
      __syncthreads();
    }
  }
  const double ratios[3] = {0.5, 1.0, 2.0};
  for (int p = tid; p < PRE; p += 1024) {
    unsigned idx = seli[p];
    int a = (int)(idx % 3u);
    int pos = (int)(idx / 3u);
    int ypix = pos / 100, xpix = pos % 100;
    double sx = (double)(xpix * 8), sy = (double)(ypix * 8);
    double sq = sqrt(ratios[a]);
    double w2 = (64.0 / sq) * 0.5;
    double h2 = (64.0 * sq) * 0.5;
    float x1a = (float)(sx - w2), y1a = (float)(sy - h2);
    float x2a = (float)(sx + w2), y2a = (float)(sy + h2);
    double wa = (double)x2a - (double)x1a;
    double ha = (double)y2a - (double)y1a;
    double cxa = (double)x1a + 0.5 * wa, cya = (double)y1a + 0.5 * ha;
    const double* dd = deltas64 + ((size_t)b * NANCH + idx) * 4;
    double dx = dd[0], dy = dd[1];
    double dw = fmin(dd[2], CLAMPD), dh = fmin(dd[3], CLAMPD);
    double cx = dx * wa + cxa, cy = dy * ha + cya;
    double w = exp(dw) * wa, h = exp(dh) * ha;
    double bx1 = fmin(fmax(cx - 0.5 * w, 0.0), 800.0);
    double by1 = fmin(fmax(cy - 0.5 * h, 0.0), 800.0);
    double bx2 = fmin(fmax(cx + 0.5 * w, 0.0), 800.0);
    double by2 = fmin(fmax(cy + 0.5 * h, 0.0), 800.0);
    double* bo = boxesd + ((size_t)b * PRE + p) * 4;
    bo[0] = bx1; bo[1] = by1; bo[2] = bx2; bo[3] = by2;
    float* bf = boxesf + ((size_t)b * PRE + p) * 4;
    bf[0] = (float)bx1; bf[1] = (float)by1; bf[2] = (float)bx2; bf[3] = (float)by2;
  }
}

// ---------------- suppression matrix (FP64 IoU) ----------------
__global__ void supmat_k(const double* __restrict__ boxes, unsigned* __restrict__ sup) {
  int b = blockIdx.y;
  int gt = blockIdx.x * 256 + threadIdx.x;
  int i = gt >> 6, w = gt & 63;
  if (i >= PRE) return;
  const double* bb = boxes + (size_t)b * PRE * 4;
  double x1 = bb[i * 4 + 0], y1 = bb[i * 4 + 1], x2 = bb[i * 4 + 2], y2 = bb[i * 4 + 3];
  double a1 = (x2 - x1) * (y2 - y1);
  unsigned m = 0;
  int j0 = w * 32;
  for (int jj = 0; jj < 32; ++jj) {
    int j = j0 + jj;
    if (j >= PRE) break;
    if (j > i) {
      double u1 = bb[j * 4 + 0], v1 = bb[j * 4 + 1], u2 = bb[j * 4 + 2], v2 = bb[j * 4 + 3];
      double ltx = fmax(x1, u1), lty = fmax(y1, v1);
      double rbx = fmin(x2, u2), rby = fmin(y2, v2);
      double ww = fmax(rbx - ltx, 0.0), hh = fmax(rby - lty, 0.0);
      double inter = ww * hh;
      double a2 = (u2 - u1) * (v2 - v1);
      double iou = inter / (a1 + a2 - inter + 1e-9);
      if (iou > 0.7) m |= 1u << jj;
    }
  }
  sup[((size_t)b * 2048 + i) * 64 + w] = m;
}

// ---------------- sequential NMS: readlane walk + 4-wave parallel kill-OR ----------------
__global__ void nms_emit_k(const unsigned* __restrict__ sup, const float* __restrict__ boxes,
                           float* __restrict__ rois) {
  int b = blockIdx.x;
  int tid = threadIdx.x;
  int wv = tid >> 6, lane = tid & 63;
  __shared__ unsigned buf[2][4096];
  __shared__ unsigned kill_s[4][64];
  __shared__ unsigned aw_s[64];
  __shared__ unsigned sh_cm0, sh_cm1;
  __shared__ unsigned pre[64];
  __shared__ unsigned sh_m;
  const unsigned* sb = sup + (size_t)b * 2048 * 64;

  for (int i = tid; i < 4096; i += 256) buf[0][i] = sb[i];
  if (tid < 64) aw_s[tid] = (tid < 62) ? 0xFFFFFFFFu : (tid == 62 ? 0xFFFFu : 0u);
  __syncthreads();

  for (int c = 0; c < 32; ++c) {
    const unsigned* B = buf[c & 1];
    if (wv == 0) {
      unsigned rlo = B[lane * 64 + 2 * c];
      unsigned rhi = B[lane * 64 + 2 * c + 1];
      unsigned clo = __builtin_amdgcn_readfirstlane(aw_s[2 * c]);
      unsigned chi = __builtin_amdgcn_readfirstlane(aw_s[2 * c + 1]);
      unsigned long long cm = (unsigned long long)clo | ((unsigned long long)chi << 32);
      unsigned long long m = cm;
      while (m) {
        int ii = __builtin_ctzll(m);
        unsigned klo = (unsigned)__builtin_amdgcn_readlane((int)rlo, ii);
        unsigned khi = (unsigned)__builtin_amdgcn_readlane((int)rhi, ii);
        unsigned long long kd = (unsigned long long)klo | ((unsigned long long)khi << 32);
        cm &= ~kd;
        m = cm & ~((2ULL << ii) - 1ULL);
      }
      if (lane == 0) { sh_cm0 = (unsigned)cm; sh_cm1 = (unsigned)(cm >> 32); }
    } else if (c + 1 < 32) {
      for (int i = tid - 64; i < 4096; i += 192) buf[(c + 1) & 1][i] = sb[(size_t)(c + 1) * 4096 + i];
    }
    __syncthreads();
    {
      unsigned long long cm = (unsigned long long)sh_cm0 | ((unsigned long long)sh_cm1 << 32);
      unsigned k = 0;
      unsigned long long m2 = cm;
      int cnt = 0;
      while (m2) {
        int ii = __builtin_ctzll(m2);
        m2 &= m2 - 1;
        if ((cnt & 3) == wv) k |= B[ii * 64 + lane];
        ++cnt;
      }
      kill_s[wv][lane] = k;
    }
    __syncthreads();
    if (tid < 64)
      aw_s[tid] &= ~(kill_s[0][tid] | kill_s[1][tid] | kill_s[2][tid] | kill_s[3][tid]);
    __syncthreads();
  }
  if (tid == 0) {
    unsigned m = 0;
    for (int w = 0; w < 64; ++w) { pre[w] = m; m += __popc(aw_s[w]); }
    sh_m = m;
  }
  __syncthreads();
  unsigned m = sh_m;
  for (int i = tid; i < PRE; i += 256) {
    int w = i >> 5;
    unsigned word = aw_s[w];
    unsigned lower = word & ((1u << (i & 31)) - 1u);
    unsigned rank = pre[w] + __popc(lower);
    bool al = (word >> (i & 31)) & 1u;
    unsigned dst;
    if (al) {
      if (rank >= POST) continue;
      dst = rank;
    } else {
      unsigned dpos = m + ((unsigned)i - rank);
      if (dpos >= POST) continue;
      dst = dpos;
    }
    const float4 v = *(const float4*)(boxes + ((size_t)b * PRE + i) * 4);
    *(float4*)(rois + ((size_t)b * POST + dst) * 4) = v;
  }
}

// ---------------- roi align (7x7, SR=2) over NHWC f32 features -> bf16 pooled ----------------
__global__ void roi_align_k(const float* __restrict__ featT, const float* __restrict__ rois,
                            __hip_bfloat16* __restrict__ pooled) {
  __shared__ float slx[14], sly[14];
  __shared__ int sx0[14], sx1[14], sy0[14], sy1[14];
  int tid = threadIdx.x;
  int gro = blockIdx.x;
  int b = gro / POST;
  const float* r = rois + (size_t)gro * 4;
  if (tid < 14) {
    float x1 = r[0] * 0.125f, x2 = r[2] * 0.125f;
    float bw = (x2 - x1) / 7.0f;
    float k = ((float)tid + 0.5f) / 2.0f;
    float xs = fminf(fmaxf(x1 + bw * k, 0.f), 99.f);
    float x0f = floorf(xs);
    int x0i = (int)x0f;
    sx0[tid] = x0i; sx1[tid] = min(x0i + 1, 99); slx[tid] = xs - x0f;
  } else if (tid < 28) {
    int s = tid - 14;
    float y1 = r[1] * 0.125f, y2 = r[3] * 0.125f;
    float bh = (y2 - y1) / 7.0f;
    float k = ((float)s + 0.5f) / 2.0f;
    float ys = fminf(fmaxf(y1 + bh * k, 0.f), 99.f);
    float y0f = floorf(ys);
    int y0i = (int)y0f;
    sy0[s] = y0i; sy1[s] = min(y0i + 1, 99); sly[s] = ys - y0f;
  }
  __syncthreads();
  int c = tid;
  const float* fb = featT + (size_t)b * NPOS * 256 + c;
  __hip_bfloat16* outp = pooled + (size_t)gro * 12544 + (size_t)c * 49;
  for (int ph = 0; ph < 7; ++ph) {
    for (int pw = 0; pw < 7; ++pw) {
      float acc = 0.f;
#pragma unroll
      for (int sy = 0; sy < 2; ++sy) {
        int yi = ph * 2 + sy;
        int y0 = sy0[yi], y1 = sy1[yi];
        float ly = sly[yi], hy = 1.f - ly;
#pragma unroll
        for (int sx = 0; sx < 2; ++sx) {
          int xi = pw * 2 + sx;
          int x0 = sx0[xi], x1 = sx1[xi];
          float lx = slx[xi], hx = 1.f - lx;
          float v00 = fb[(size_t)(y0 * 100 + x0) * 256];
          float v01 = fb[(size_t)(y0 * 100 + x1) * 256];
          float v10 = fb[(size_t)(y1 * 100 + x0) * 256];
          float v11 = fb[(size_t)(y1 * 100 + x1) * 256];
          acc += hy * hx * v00 + hy * lx * v01 + ly * hx * v10 + ly * lx * v11;
        }
      }
      outp[ph * 7 + pw] = __float2bfloat16(acc * 0.25f);
    }
  }
}

// ---------------- weight transpose+convert: w f32[K][N] -> wt bf16[N][K] ----------------
__global__ void wt_bf16_k(const float* __restrict__ w, __hip_bfloat16* __restrict__ wt,
                          int K, int N) {
  __shared__ float tile[32][33];
  int k0 = blockIdx.x * 32, n0 = blockIdx.y * 32;
  int tx = threadIdx.x & 31, ty = threadIdx.x >> 5;
  for (int r = 0; r < 4; ++r)
    tile[ty + r * 8][tx] = w[(size_t)(k0 + ty + r * 8) * N + n0 + tx];
  __syncthreads();
  for (int r = 0; r < 4; ++r)
    wt[(size_t)(n0 + ty + r * 8) * K + k0 + tx] = __float2bfloat16(tile[tx][ty + r * 8]);
}

// ---------------- bf16 MFMA GEMM (128x128 tile; used for FC2) ----------------
__global__ __launch_bounds__(256) void gemm_bf16_k(const __hip_bfloat16* __restrict__ A,
                                                   const __hip_bfloat16* __restrict__ Bt,
                                                   const float* __restrict__ bias,
                                                   __hip_bfloat16* __restrict__ C,
                                                   int N, int K, int relu) {
  __shared__ __hip_bfloat16 As[128 * 64];
  __shared__ __hip_bfloat16 Bs[128 * 64];
  const int t = threadIdx.x;
  const int w = t >> 6;
  const int lane = t & 63;
  const int lr = lane & 15, lg = lane >> 4;
  const int wr = w >> 1, wc = w & 1;
  const int m0 = blockIdx.y * 128, n0 = blockIdx.x * 128;

  f32x4v acc[4][4];
#pragma unroll
  for (int i = 0; i < 4; ++i)
#pragma unroll
    for (int j = 0; j < 4; ++j)
#pragma unroll
      for (int r = 0; r < 4; ++r) acc[i][j][r] = 0.f;

  int srow[4], soff[4];
#pragma unroll
  for (int i = 0; i < 4; ++i) {
    int c = i * 256 + t;
    int row = c >> 3, ccd = c & 7;
    srow[i] = row;
    soff[i] = (ccd ^ (row & 7)) * 8;
  }
  int arow[4], brow[4], sk[2];
#pragma unroll
  for (int ms = 0; ms < 4; ++ms) arow[ms] = (wr * 64 + ms * 16 + lr) * 128;
#pragma unroll
  for (int ns = 0; ns < 4; ++ns) brow[ns] = (wc * 64 + ns * 16 + lr) * 128;
#pragma unroll
  for (int kk = 0; kk < 2; ++kk) sk[kk] = (((kk * 4 + lg) ^ (lr & 7)) * 16);

  for (int k0 = 0; k0 < K; k0 += 64) {
    __syncthreads();
#pragma unroll
    for (int i = 0; i < 4; ++i) {
      const __hip_bfloat16* ga = A + (size_t)(m0 + srow[i]) * K + k0 + soff[i];
      async_load16(ga, (char*)As + ((i * 256 + w * 64) * 16));
    }
#pragma unroll
    for (int i = 0; i < 4; ++i) {
      const __hip_bfloat16* gb = Bt + (size_t)(n0 + srow[i]) * K + k0 + soff[i];
      async_load16(gb, (char*)Bs + ((i * 256 + w * 64) * 16));
    }
    __syncthreads();

    bf16x8v af[2][4], bf[2][4];
#pragma unroll
    for (int kk = 0; kk < 2; ++kk) {
#pragma unroll
      for (int ms = 0; ms < 4; ++ms)
        af[kk][ms] = *(const bf16x8v*)((const char*)As + arow[ms] + sk[kk]);
#pragma unroll
      for (int ns = 0; ns < 4; ++ns)
        bf[kk][ns] = *(const bf16x8v*)((const char*)Bs + brow[ns] + sk[kk]);
    }
#pragma unroll
    for (int ms = 0; ms < 4; ++ms)
#pragma unroll
      for (int ns = 0; ns < 4; ++ns) {
        acc[ms][ns] = __builtin_amdgcn_mfma_f32_16x16x32_bf16(af[0][ms], bf[0][ns], acc[ms][ns], 0, 0, 0);
        acc[ms][ns] = __builtin_amdgcn_mfma_f32_16x16x32_bf16(af[1][ms], bf[1][ns], acc[ms][ns], 0, 0, 0);
      }
  }

#pragma unroll
  for (int ms = 0; ms < 4; ++ms) {
    int gm = m0 + wr * 64 + ms * 16 + lg * 4;
#pragma unroll
    for (int ns = 0; ns < 4; ++ns) {
      int gn = n0 + wc * 64 + ns * 16 + lr;
      float bv = bias[gn];
#pragma unroll
      for (int r = 0; r < 4; ++r) {
        float v = acc[ms][ns][r] + bv;
        if (relu) v = fmaxf(v, 0.f);
        C[(size_t)(gm + r) * N + gn] = __float2bfloat16(v);
      }
    }
  }
}

// ---------------- FC1 K-split GEMM: part[ks][m][n] (fp32, no bias) ----------------
#define FC1K 12544
#define FC1KS 2
#define FC1KSEG (FC1K / FC1KS)
__global__ __launch_bounds__(256) void gemm_part_k(const __hip_bfloat16* __restrict__ A,
                                                   const __hip_bfloat16* __restrict__ Bt,
                                                   float* __restrict__ part) {
  __shared__ __hip_bfloat16 As[128 * 64];
  __shared__ __hip_bfloat16 Bs[64 * 64];
  const int t = threadIdx.x;
  const int w = t >> 6;
  const int lane = t & 63;
  const int lr = lane & 15, lg = lane >> 4;
  const int wr = w >> 1, wc = w & 1;
  const int m0 = blockIdx.y * 128, n0 = blockIdx.x * 64;
  const int ks = blockIdx.z;
  const int kbase = ks * FC1KSEG;

  f32x4v acc[4][2];
#pragma unroll
  for (int i = 0; i < 4; ++i)
#pragma unroll
    for (int j = 0; j < 2; ++j)
#pragma unroll
      for (int r = 0; r < 4; ++r) acc[i][j][r] = 0.f;

  int srow[4], soff[4];
#pragma unroll
  for (int i = 0; i < 4; ++i) {
    int c = i * 256 + t;
    int row = c >> 3, ccd = c & 7;
    srow[i] = row;
    soff[i] = (ccd ^ (row & 7)) * 8;
  }
  int arow[4], brow[2], sk[2];
#pragma unroll
  for (int ms = 0; ms < 4; ++ms) arow[ms] = (wr * 64 + ms * 16 + lr) * 128;
#pragma unroll
  for (int ns = 0; ns < 2; ++ns) brow[ns] = (wc * 32 + ns * 16 + lr) * 128;
#pragma unroll
  for (int kk = 0; kk < 2; ++kk) sk[kk] = (((kk * 4 + lg) ^ (lr & 7)) * 16);

  for (int k0 = 0; k0 < FC1KSEG; k0 += 64) {
    __syncthreads();
#pragma unroll
    for (int i = 0; i < 4; ++i) {
      const __hip_bfloat16* ga = A + (size_t)(m0 + srow[i]) * FC1K + kbase + k0 + soff[i];
      async_load16(ga, (char*)As + ((i * 256 + w * 64) * 16));
    }
#pragma unroll
    for (int i = 0; i < 2; ++i) {
      const __hip_bfloat16* gb = Bt + (size_t)(n0 + srow[i]) * FC1K + kbase + k0 + soff[i];
      async_load16(gb, (char*)Bs + ((i * 256 + w * 64) * 16));
    }
    __syncthreads();

    bf16x8v af[2][4], bf[2][2];
#pragma unroll
    for (int kk = 0; kk < 2; ++kk) {
#pragma unroll
      for (int ms = 0; ms < 4; ++ms)
        af[kk][ms] = *(const bf16x8v*)((const char*)As + arow[ms] + sk[kk]);
#pragma unroll
      for (int ns = 0; ns < 2; ++ns)
        bf[kk][ns] = *(const bf16x8v*)((const char*)Bs + brow[ns] + sk[kk]);
    }
#pragma unroll
    for (int ms = 0; ms < 4; ++ms)
#pragma unroll
      for (int ns = 0; ns < 2; ++ns) {
        acc[ms][ns] = __builtin_amdgcn_mfma_f32_16x16x32_bf16(af[0][ms], bf[0][ns], acc[ms][ns], 0, 0, 0);
        acc[ms][ns] = __builtin_amdgcn_mfma_f32_16x16x32_bf16(af[1][ms], bf[1][ns], acc[ms][ns], 0, 0, 0);
      }
  }

  float* pb = part + (size_t)ks * 2048 * 1024;
#pragma unroll
  for (int ms = 0; ms < 4; ++ms) {
    int gm = m0 + wr * 64 + ms * 16 + lg * 4;
#pragma unroll
    for (int ns = 0; ns < 2; ++ns) {
      int gn = n0 + wc * 32 + ns * 16 + lr;
#pragma unroll
      for (int r = 0; r < 4; ++r)
        pb[(size_t)(gm + r) * 1024 + gn] = acc[ms][ns][r];
    }
  }
}

// ---------------- reduce partials: x1 = bf16(relu(p0+p1+bias)) ----------------
__global__ void reduce_bias_relu_k(const float* __restrict__ part, const float* __restrict__ bias,
                                   __hip_bfloat16* __restrict__ x1) {
  int i4 = blockIdx.x * 256 + threadIdx.x;
  if (i4 >= 524288) return;
  const float4 a = ((const float4*)part)[i4];
  const float4 b = ((const float4*)part)[524288 + i4];
  const float4 bv = ((const float4*)bias)[i4 & 255];
  float v0 = fmaxf(a.x + b.x + bv.x, 0.f);
  float v1 = fmaxf(a.y + b.y + bv.y, 0.f);
  float v2 = fmaxf(a.z + b.z + bv.z, 0.f);
  float v3 = fmaxf(a.w + b.w + bv.w, 0.f);
  __hip_bfloat16* o = x1 + (size_t)i4 * 4;
  o[0] = __float2bfloat16(v0);
  o[1] = __float2bfloat16(v1);
  o[2] = __float2bfloat16(v2);
  o[3] = __float2bfloat16(v3);
}

// ---------------- final heads ----------------
__global__ void final_heads_k(const __hip_bfloat16* __restrict__ x2,
                              const float* __restrict__ cls_w, const float* __restrict__ cls_b,
                              const float* __restrict__ reg_w, const float* __restrict__ reg_b,
                              float* __restrict__ out) {
  __shared__ float wl[1024][10];
  int tid = threadIdx.x;
  for (int i = tid; i < 1024 * 10; i += 256) {
    int k = i / 10, n = i % 10;
    wl[k][n] = (n < 2) ? cls_w[k * 2 + n] : reg_w[k * 8 + (n - 2)];
  }
  __syncthreads();
  int gt = blockIdx.x * 256 + tid;
  if (gt >= 2 * POST * 10) return;
  int mg = gt / 10, n = gt % 10;
  const __hip_bfloat16* xr = x2 + (size_t)mg * 1024;
  float acc = 0.f;
  for (int k = 0; k < 1024; ++k) acc += __bfloat162float(xr[k]) * wl[k][n];
  acc += (n < 2) ? cls_b[n] : reg_b[n - 2];
  out[(size_t)mg * 10 + n] = acc;
}

extern "C" void kernel_launch(void* const* d_in, const int* in_sizes, int n_in,
                              void* d_out, int out_size, void* d_ws, size_t ws_size,
                              hipStream_t stream) {
  const float* features   = (const float*)d_in[0];
  const float* rpn_conv_w = (const float*)d_in[1];
  const float* rpn_conv_b = (const float*)d_in[2];
  const float* rpn_cls_w  = (const float*)d_in[3];
  const float* rpn_cls_b  = (const float*)d_in[4];
  const float* rpn_bbox_w = (const float*)d_in[5];
  const float* rpn_bbox_b = (const float*)d_in[6];
  const float* fc1_w = (const float*)d_in[7];
  const float* fc1_b = (const float*)d_in[8];
  const float* fc2_w = (const float*)d_in[9];
  const float* fc2_b = (const float*)d_in[10];
  const float* cls_w = (const float*)d_in[11];
  const float* cls_b = (const float*)d_in[12];
  const float* reg_w = (const float*)d_in[13];
  const float* reg_b = (const float*)d_in[14];
  float* out = (float*)d_out;

  char* ws = (char*)d_ws;
  size_t off = 0;
  auto alloc = [&](size_t bytes) -> void* {
    off = (off + 255) & ~(size_t)255;
    void* p = ws + off;
    off += bytes;
    return p;
  };
  // persistent buffers
  float* featT = (float*)alloc((size_t)2 * NPOS * 256 * 4);
  float* rois  = (float*)alloc((size_t)2 * POST * 4 * 4);
  __hip_bfloat16* w1t = (__hip_bfloat16*)alloc((size_t)1024 * 12544 * 2);
  __hip_bfloat16* w2t = (__hip_bfloat16*)alloc((size_t)1024 * 1024 * 2);
  __hip_bfloat16* x1  = (__hip_bfloat16*)alloc((size_t)2048 * 1024 * 2);
  __hip_bfloat16* x2  = (__hip_bfloat16*)alloc((size_t)2048 * 1024 * 2);
  // aliased region: RPN intermediates (dead after nms), then pooled + fc1 partials
  off = (off + 255) & ~(size_t)255;
  size_t region = off;
  double*   wT64r    = (double*)alloc((size_t)589824 * 8);
  __hip_bfloat16* fpadB = (__hip_bfloat16*)alloc((size_t)2 * FPH * FPW * 256 * 2);
  __hip_bfloat16* wBt   = (__hip_bfloat16*)alloc((size_t)589824 * 2);
  // union: {t32 (20.5MB) + objf (0.24MB)} before select_k  |  t64p (50.3MB) after
  off = (off + 255) & ~(size_t)255;
  size_t uni = off;
  float*  t32  = (float*)(ws + uni);
  float*  objf = (float*)(ws + uni + (((size_t)2 * NPOS * 256 * 4 + 255) & ~(size_t)255));
  double* t64p = (double*)(ws + uni);
  size_t uni_sz = (size_t)3 * 2 * RESQ * 256 * 8;   // 50.3 MB > t32+objf
  off = uni + uni_sz;
  double*   obj64    = (double*)alloc((size_t)2 * NANCH * 8);
  double*   deltas64 = (double*)alloc((size_t)2 * NANCH * 4 * 8);
  double*   boxesd   = (double*)alloc((size_t)2 * PRE * 4 * 8);
  float*    boxesf   = (float*)alloc((size_t)2 * PRE * 4 * 4);
  unsigned* sup      = (unsigned*)alloc((size_t)2 * 2048 * 64 * 4);
  unsigned* cand     = (unsigned*)alloc((size_t)2 * RESQ * 4);
  int*      poslist  = (int*)alloc((size_t)2 * RESQ * 4);
  int*      counts   = (int*)alloc(64);
  // pooled + fc1 partials alias the whole RPN region (everything above is dead post-nms)
  __hip_bfloat16* pooled = (__hip_bfloat16*)(ws + region);
  size_t pooled_sz = (size_t)2048 * 12544 * 2;                 // 51.4 MB
  float* fc1part = (float*)(ws + region + ((pooled_sz + 255) & ~(size_t)255));
  size_t part_end = region + ((pooled_sz + 255) & ~(size_t)255) + (size_t)FC1KS * 2048 * 1024 * 4;
  if (off < part_end) off = part_end;
  (void)ws_size; (void)in_sizes; (void)n_in; (void)out_size;

  repack_w_k<<<2304, 256, 0, stream>>>(rpn_conv_w, wT64r);
  wbt_k<<<2304, 256, 0, stream>>>(rpn_conv_w, wBt);
  transpose_feat_k<<<dim3(313, 8, 2), 256, 0, stream>>>(features, featT);
  fpad_zero_k<<<3366, 256, 0, stream>>>(fpadB);
  fpad_fill_k<<<dim3(313, 8, 2), 256, 0, stream>>>(features, fpadB);
  conv_mfma_k<<<dim3(2, 200), 256, 0, stream>>>(fpadB, wBt, rpn_conv_b, t32);
  rpn_obj_k<<<79, 256, 0, stream>>>(t32, rpn_cls_w, rpn_cls_b, objf);
  select_k<<<2, 1024, 0, stream>>>(objf, cand, poslist, counts, 8e-3f);
  rescore_t3_k<<<dim3(4, RESQ / 64, 6), 256, 0, stream>>>(featT, wT64r, poslist, counts, t64p);
  rescore_heads_k<<<dim3(RESQ / 16, 2), 256, 0, stream>>>(t64p, rpn_conv_b, poslist, counts,
                                                          rpn_cls_w, rpn_cls_b, rpn_bbox_w,
                                                          rpn_bbox_b, obj64, deltas64);
  topk_decode_k<<<2, 1024, 0, stream>>>(cand, counts, obj64, deltas64, boxesd, boxesf);
  supmat_k<<<dim3(512, 2), 256, 0, stream>>>(boxesd, sup);
  nms_emit_k<<<2, 256, 0, stream>>>(sup, boxesf, rois);
  wt_bf16_k<<<dim3(392, 32), 256, 0, stream>>>(fc1_w, w1t, 12544, 1024);
  wt_bf16_k<<<dim3(32, 32), 256, 0, stream>>>(fc2_w, w2t, 1024, 1024);
  roi_align_k<<<2 * POST, 256, 0, stream>>>(featT, rois, pooled);
  gemm_part_k<<<dim3(16, 16, FC1KS), 256, 0, stream>>>(pooled, w1t, fc1part);
  reduce_bias_relu_k<<<2048, 256, 0, stream>>>(fc1part, fc1_b, x1);
  gemm_bf16_k<<<dim3(8, 16), 256, 0, stream>>>(x1, w2t, fc2_b, x2, 1024, 1024, 1);
  final_heads_k<<<79, 256, 0, stream>>>(x2, cls_w, cls_b, reg_w, reg_b, out);
}